// Round 10
// baseline (7493.741 us; speedup 1.0000x reference)
//
#include <hip/hip_runtime.h>
#include <hip/hip_fp16.h>

typedef __attribute__((ext_vector_type(8))) short s16x8;
typedef __attribute__((ext_vector_type(8))) _Float16 f16x8;
typedef __attribute__((ext_vector_type(4))) float f32x4;

// ---------------------------------------------------------------------------
// fp32 -> fp16 conversion (vectorized, grid-stride)
// ---------------------------------------------------------------------------
__global__ void cvt_f32_to_f16_kernel(const float* __restrict__ in,
                                      __half* __restrict__ out, long n) {
  long i = (long)blockIdx.x * blockDim.x + threadIdx.x;
  long stride = (long)gridDim.x * blockDim.x;
  const float4* p4 = (const float4*)in;
  for (long j = i; j * 8 < n; j += stride) {
    float4 a = p4[j * 2];
    float4 b = p4[j * 2 + 1];
    union { s16x8 v; __half2 h2[4]; } w;
    w.h2[0] = __floats2half2_rn(a.x, a.y);
    w.h2[1] = __floats2half2_rn(a.z, a.w);
    w.h2[2] = __floats2half2_rn(b.x, b.y);
    w.h2[3] = __floats2half2_rn(b.z, b.w);
    *(s16x8*)(out + j * 8) = w.v;
  }
}

// ---------------------------------------------------------------------------
// Dequant 8 int4-in-int32 -> 8 fp16: f16(64+q)=0x5400|(q<<4); w = b*s-(64+z)*s
// ---------------------------------------------------------------------------
__device__ __forceinline__ s16x8 dq_compute(int4 q0, int4 q1, float s, float z) {
  __half hs = __float2half(s);
  __half2 s2 = __halves2half2(hs, hs);
  __half hc = __float2half(-(64.f + z) * s);
  __half2 c2 = __halves2half2(hc, hc);
  uint32_t b0 = 0x54005400u + ((uint32_t)q0.x << 4) + ((uint32_t)q0.y << 20);
  uint32_t b1 = 0x54005400u + ((uint32_t)q0.z << 4) + ((uint32_t)q0.w << 20);
  uint32_t b2 = 0x54005400u + ((uint32_t)q1.x << 4) + ((uint32_t)q1.y << 20);
  uint32_t b3 = 0x54005400u + ((uint32_t)q1.z << 4) + ((uint32_t)q1.w << 20);
  union { s16x8 v; __half2 h2[4]; } w;
  w.h2[0] = __hfma2(*(__half2*)&b0, s2, c2);
  w.h2[1] = __hfma2(*(__half2*)&b1, s2, c2);
  w.h2[2] = __hfma2(*(__half2*)&b2, s2, c2);
  w.h2[3] = __hfma2(*(__half2*)&b3, s2, c2);
  return w.v;
}

// bijective XCD swizzle (m204): consecutive logical ids land on the same XCD.
__device__ __forceinline__ int xcd_swz(int w0, int nwg) {
  const int q = nwg >> 3, r = nwg & 7;
  const int xcd = w0 & 7, idx = w0 >> 3;
  const int base = (xcd < r) ? xcd * (q + 1) : r * (q + 1) + (xcd - r) * q;
  return base + idx;
}

// ---------------------------------------------------------------------------
// gate/up GEMM, M-chunked, full-I: P = Xh @ Wq^T (dequant inline).
// EPI=0: Pan = fp16(acc).  EPI=1: Pan = silu(Pan) * acc  (in-place h)
// BM=128, BN=128, BK=64. 256 thr (4 waves: 2M x 2N, 64x64 each).
// Dbuf LDS 64 KB -> 2 independent blocks/CU; 1-deep reg prefetch.
// ---------------------------------------------------------------------------
template <int EPI>
__global__ __launch_bounds__(256, 2)
void qgemm_x_kernel(const __half* __restrict__ Xh,
                    const int* __restrict__ Q,
                    const float* __restrict__ S, const float* __restrict__ Z,
                    __half* __restrict__ Pan, int mbs) {
  constexpr int H = 4096, I = 11008, G = 32;
  const int wg = xcd_swz(blockIdx.x, gridDim.x);
  const int mb = wg % mbs;          // mb fastest: neighbors share the W panel
  const int nb = wg / mbs;
  const int m0 = mb * 128;
  const int n0 = nb * 128;
  const int tid = threadIdx.x;
  const int lane = tid & 63;
  const int wave = tid >> 6;
  const int wm = (wave >> 1) * 64, wn = (wave & 1) * 64;
  const int l15 = lane & 15, lq = lane >> 4;
  const int rsw = (l15 & 7) << 3;

  __shared__ __half As[2][128][64];   // 32 KB
  __shared__ __half Bs[2][128][64];   // 32 KB

  f32x4 acc[4][4];
#pragma unroll
  for (int i = 0; i < 4; ++i)
#pragma unroll
    for (int j = 0; j < 4; ++j) acc[i][j] = {0.f, 0.f, 0.f, 0.f};

  // staging maps: one row, 32 cols per thread (A and B identical split)
  const int arow = tid >> 1, acol0 = (tid & 1) * 32, asw = (arow & 7) << 3;
  const __half* aP = Xh + (size_t)(m0 + arow) * H + acol0;
  const int*    qP = Q  + (size_t)(n0 + arow) * H + acol0;
  const float*  sP = S + (size_t)(n0 + arow) * G;
  const float*  zP = Z + (size_t)(n0 + arow) * G;

  s16x8 apf[4];
  int4  qpf[8];
  float spf, zpf;

  // ---- prologue: load tile 0 to regs, write buf 0 ----
#pragma unroll
  for (int i = 0; i < 4; ++i) apf[i] = ((const s16x8*)aP)[i];
#pragma unroll
  for (int i = 0; i < 8; ++i) qpf[i] = ((const int4*)qP)[i];
  spf = sP[0]; zpf = zP[0];
#pragma unroll
  for (int i = 0; i < 4; ++i) *(s16x8*)&As[0][arow][(acol0 + i * 8) ^ asw] = apf[i];
#pragma unroll
  for (int i = 0; i < 4; ++i)
    *(s16x8*)&Bs[0][arow][(acol0 + i * 8) ^ asw] = dq_compute(qpf[2 * i], qpf[2 * i + 1], spf, zpf);
  __syncthreads();

  int p = 0;
  const int nt = H / 64;
  for (int t = 0; t < nt; ++t) {
    if (t + 1 < nt) {
      const int k1 = (t + 1) * 64;
#pragma unroll
      for (int i = 0; i < 4; ++i) apf[i] = ((const s16x8*)(aP + k1))[i];
#pragma unroll
      for (int i = 0; i < 8; ++i) qpf[i] = ((const int4*)(qP + k1))[i];
      spf = sP[k1 >> 7]; zpf = zP[k1 >> 7];
    }
    // ---- MFMA on tile t (next-tile loads in flight) ----
    __builtin_amdgcn_s_setprio(1);
#pragma unroll
    for (int kk = 0; kk < 2; ++kk) {
      const int cbase = (kk * 32 + lq * 8) ^ rsw;
      f16x8 af[4];
#pragma unroll
      for (int i = 0; i < 4; ++i)
        af[i] = *(const f16x8*)&As[p][wm + i * 16 + l15][cbase];
#pragma unroll
      for (int j = 0; j < 4; ++j) {
        f16x8 bf = *(const f16x8*)&Bs[p][wn + j * 16 + l15][cbase];
#pragma unroll
        for (int i = 0; i < 4; ++i)
          acc[i][j] = __builtin_amdgcn_mfma_f32_16x16x32_f16(af[i], bf, acc[i][j], 0, 0, 0);
      }
    }
    __builtin_amdgcn_s_setprio(0);
    // ---- write tile t+1 into the other buffer ----
    if (t + 1 < nt) {
#pragma unroll
      for (int i = 0; i < 4; ++i) *(s16x8*)&As[p ^ 1][arow][(acol0 + i * 8) ^ asw] = apf[i];
#pragma unroll
      for (int i = 0; i < 4; ++i)
        *(s16x8*)&Bs[p ^ 1][arow][(acol0 + i * 8) ^ asw] = dq_compute(qpf[2 * i], qpf[2 * i + 1], spf, zpf);
    }
    __syncthreads();
    p ^= 1;
  }
  // ---- epilogue ----
#pragma unroll
  for (int i = 0; i < 4; ++i)
#pragma unroll
    for (int j = 0; j < 4; ++j)
#pragma unroll
      for (int r = 0; r < 4; ++r) {
        const int row = m0 + wm + i * 16 + lq * 4 + r;
        const int col = n0 + wn + j * 16 + l15;
        const size_t idx = (size_t)row * I + col;
        if (EPI == 0) {
          Pan[idx] = __float2half(acc[i][j][r]);
        } else {
          float g = __half2float(Pan[idx]);
          float u = acc[i][j][r];
          Pan[idx] = __float2half((g / (1.f + __expf(-g))) * u);
        }
      }
}

// ---------------------------------------------------------------------------
// Down GEMM, M-chunked, full-K: out = h @ Wd^T. Same structure. K=11008.
// ---------------------------------------------------------------------------
__global__ __launch_bounds__(256, 2)
void down_kernel(const __half* __restrict__ Hws,
                 const int* __restrict__ Qd,
                 const float* __restrict__ Sd, const float* __restrict__ Zd,
                 float* __restrict__ Out, int mbs) {
  constexpr int K = 11008, N = 4096, G = 86;
  const int wg = xcd_swz(blockIdx.x, gridDim.x);
  const int mb = wg % mbs;
  const int nb = wg / mbs;
  const int m0 = mb * 128, n0 = nb * 128;
  const int tid = threadIdx.x;
  const int lane = tid & 63;
  const int wave = tid >> 6;
  const int wm = (wave >> 1) * 64, wn = (wave & 1) * 64;
  const int l15 = lane & 15, lq = lane >> 4;
  const int rsw = (l15 & 7) << 3;

  __shared__ __half As[2][128][64];
  __shared__ __half Bs[2][128][64];

  f32x4 acc[4][4];
#pragma unroll
  for (int i = 0; i < 4; ++i)
#pragma unroll
    for (int j = 0; j < 4; ++j) acc[i][j] = {0.f, 0.f, 0.f, 0.f};

  const int arow = tid >> 1, acol0 = (tid & 1) * 32, asw = (arow & 7) << 3;
  const __half* aP = Hws + (size_t)(m0 + arow) * K + acol0;
  const int*    qP = Qd  + (size_t)(n0 + arow) * K + acol0;
  const float*  sP = Sd + (size_t)(n0 + arow) * G;
  const float*  zP = Zd + (size_t)(n0 + arow) * G;

  s16x8 apf[4];
  int4  qpf[8];
  float spf, zpf;

#pragma unroll
  for (int i = 0; i < 4; ++i) apf[i] = ((const s16x8*)aP)[i];
#pragma unroll
  for (int i = 0; i < 8; ++i) qpf[i] = ((const int4*)qP)[i];
  spf = sP[0]; zpf = zP[0];
#pragma unroll
  for (int i = 0; i < 4; ++i) *(s16x8*)&As[0][arow][(acol0 + i * 8) ^ asw] = apf[i];
#pragma unroll
  for (int i = 0; i < 4; ++i)
    *(s16x8*)&Bs[0][arow][(acol0 + i * 8) ^ asw] = dq_compute(qpf[2 * i], qpf[2 * i + 1], spf, zpf);
  __syncthreads();

  int p = 0;
  const int nt = K / 64;
  for (int t = 0; t < nt; ++t) {
    if (t + 1 < nt) {
      const int k1 = (t + 1) * 64;
#pragma unroll
      for (int i = 0; i < 4; ++i) apf[i] = ((const s16x8*)(aP + k1))[i];
#pragma unroll
      for (int i = 0; i < 8; ++i) qpf[i] = ((const int4*)(qP + k1))[i];
      spf = sP[k1 >> 7]; zpf = zP[k1 >> 7];
    }
    __builtin_amdgcn_s_setprio(1);
#pragma unroll
    for (int kk = 0; kk < 2; ++kk) {
      const int cbase = (kk * 32 + lq * 8) ^ rsw;
      f16x8 af[4];
#pragma unroll
      for (int i = 0; i < 4; ++i)
        af[i] = *(const f16x8*)&As[p][wm + i * 16 + l15][cbase];
#pragma unroll
      for (int j = 0; j < 4; ++j) {
        f16x8 bf = *(const f16x8*)&Bs[p][wn + j * 16 + l15][cbase];
#pragma unroll
        for (int i = 0; i < 4; ++i)
          acc[i][j] = __builtin_amdgcn_mfma_f32_16x16x32_f16(af[i], bf, acc[i][j], 0, 0, 0);
      }
    }
    __builtin_amdgcn_s_setprio(0);
    if (t + 1 < nt) {
#pragma unroll
      for (int i = 0; i < 4; ++i) *(s16x8*)&As[p ^ 1][arow][(acol0 + i * 8) ^ asw] = apf[i];
#pragma unroll
      for (int i = 0; i < 4; ++i)
        *(s16x8*)&Bs[p ^ 1][arow][(acol0 + i * 8) ^ asw] = dq_compute(qpf[2 * i], qpf[2 * i + 1], spf, zpf);
    }
    __syncthreads();
    p ^= 1;
  }
#pragma unroll
  for (int i = 0; i < 4; ++i)
#pragma unroll
    for (int j = 0; j < 4; ++j)
#pragma unroll
      for (int r = 0; r < 4; ++r) {
        const int row = m0 + wm + i * 16 + lq * 4 + r;
        const int col = n0 + wn + j * 16 + l15;
        Out[(size_t)row * N + col] = acc[i][j][r];
      }
}

// ---------------------------------------------------------------------------
extern "C" void kernel_launch(void* const* d_in, const int* in_sizes, int n_in,
                              void* d_out, int out_size, void* d_ws, size_t ws_size,
                              hipStream_t stream) {
  const float* x  = (const float*)d_in[0];
  const int* qg   = (const int*)d_in[1];
  const int* qu   = (const int*)d_in[2];
  const int* qd   = (const int*)d_in[3];
  const float* sg = (const float*)d_in[4];
  const float* zg = (const float*)d_in[5];
  const float* su = (const float*)d_in[6];
  const float* zu = (const float*)d_in[7];
  const float* sd = (const float*)d_in[8];
  const float* zd = (const float*)d_in[9];
  float* out = (float*)d_out;

  const int M = 8192, H = 4096, I = 11008;

  // M-chunking: x fp16 chunk + h panel chunk in ws. Mc multiple of 128.
  const size_t per_row = (size_t)(H + I) * 2;
  long mc = (long)(ws_size / per_row);
  mc &= ~127L;
  if (mc > M) mc = M;
  if (mc < 128) mc = 128;
  // equalize chunk sizes (reduces tail imbalance)
  int nch = (int)((M + mc - 1) / mc);
  long mce = ((M + nch - 1) / nch + 127) & ~127L;
  if (mce > mc) mce = mc;
  const int Mc = (int)mce;

  __half* wsx = (__half*)d_ws;
  __half* wsh = (__half*)((char*)d_ws + (size_t)Mc * H * 2);

  for (int mbase = 0; mbase < M; mbase += Mc) {
    const int rows = (M - mbase < Mc) ? (M - mbase) : Mc;
    const int mbs = rows / 128;
    cvt_f32_to_f16_kernel<<<1024, 256, 0, stream>>>(
        x + (size_t)mbase * H, wsx, (long)rows * H);
    qgemm_x_kernel<0><<<mbs * (I / 128), 256, 0, stream>>>(
        wsx, qg, sg, zg, wsh, mbs);
    qgemm_x_kernel<1><<<mbs * (I / 128), 256, 0, stream>>>(
        wsx, qu, su, zu, wsh, mbs);
    down_kernel<<<mbs * (H / 128), 256, 0, stream>>>(
        wsh, qd, sd, zd, out + (size_t)mbase * H, mbs);
  }
}

// Round 11
// 4209.536 us; speedup vs baseline: 1.7802x; 1.7802x over previous
//
#include <hip/hip_runtime.h>
#include <hip/hip_fp16.h>

typedef __attribute__((ext_vector_type(8))) short s16x8;
typedef __attribute__((ext_vector_type(8))) _Float16 f16x8;
typedef __attribute__((ext_vector_type(4))) float f32x4;

// ---------------------------------------------------------------------------
// fp32 -> fp16 conversion (vectorized, grid-stride)
// ---------------------------------------------------------------------------
__global__ void cvt_f32_to_f16_kernel(const float* __restrict__ in,
                                      __half* __restrict__ out, long n) {
  long i = (long)blockIdx.x * blockDim.x + threadIdx.x;
  long stride = (long)gridDim.x * blockDim.x;
  const float4* p4 = (const float4*)in;
  for (long j = i; j * 8 < n; j += stride) {
    float4 a = p4[j * 2];
    float4 b = p4[j * 2 + 1];
    union { s16x8 v; __half2 h2[4]; } w;
    w.h2[0] = __floats2half2_rn(a.x, a.y);
    w.h2[1] = __floats2half2_rn(a.z, a.w);
    w.h2[2] = __floats2half2_rn(b.x, b.y);
    w.h2[3] = __floats2half2_rn(b.z, b.w);
    *(s16x8*)(out + j * 8) = w.v;
  }
}

// ---------------------------------------------------------------------------
// Dequant 8 int4-in-int32 -> 8 fp16: f16(64+q)=0x5400|(q<<4); w = b*s-(64+z)*s
// ---------------------------------------------------------------------------
__device__ __forceinline__ s16x8 dq_compute(int4 q0, int4 q1, float s, float z) {
  __half hs = __float2half(s);
  __half2 s2 = __halves2half2(hs, hs);
  __half hc = __float2half(-(64.f + z) * s);
  __half2 c2 = __halves2half2(hc, hc);
  uint32_t b0 = 0x54005400u + ((uint32_t)q0.x << 4) + ((uint32_t)q0.y << 20);
  uint32_t b1 = 0x54005400u + ((uint32_t)q0.z << 4) + ((uint32_t)q0.w << 20);
  uint32_t b2 = 0x54005400u + ((uint32_t)q1.x << 4) + ((uint32_t)q1.y << 20);
  uint32_t b3 = 0x54005400u + ((uint32_t)q1.z << 4) + ((uint32_t)q1.w << 20);
  union { s16x8 v; __half2 h2[4]; } w;
  w.h2[0] = __hfma2(*(__half2*)&b0, s2, c2);
  w.h2[1] = __hfma2(*(__half2*)&b1, s2, c2);
  w.h2[2] = __hfma2(*(__half2*)&b2, s2, c2);
  w.h2[3] = __hfma2(*(__half2*)&b3, s2, c2);
  return w.v;
}

// bijective XCD swizzle (m204): consecutive logical ids land on the same XCD.
__device__ __forceinline__ int xcd_swz(int w0, int nwg) {
  const int q = nwg >> 3, r = nwg & 7;
  const int xcd = w0 & 7, idx = w0 >> 3;
  const int base = (xcd < r) ? xcd * (q + 1) : r * (q + 1) + (xcd - r) * q;
  return base + idx;
}

// ---------------------------------------------------------------------------
// gate/up GEMM, M-chunked, full-I: P = Xh @ Wq^T (dequant inline).
// EPI=0: Pan = fp16(acc).  EPI=1: Pan = silu(Pan) * acc  (in-place h)
// BM=256, BN=128, BK=64. 512 thr (8 waves: 4M x 2N, 64x64 each).
// 2-deep register prefetch (two named sets), dbuf LDS. ~770cyc load coverage.
// ---------------------------------------------------------------------------
template <int EPI>
__global__ __launch_bounds__(512, 2)
void qgemm_x_kernel(const __half* __restrict__ Xh,
                    const int* __restrict__ Q,
                    const float* __restrict__ S, const float* __restrict__ Z,
                    __half* __restrict__ Pan, int mbs) {
  constexpr int H = 4096, I = 11008, G = 32;
  const int wg = xcd_swz(blockIdx.x, gridDim.x);
  const int mb = wg % mbs;          // mb fastest: neighbors share the W panel
  const int nb = wg / mbs;
  const int m0 = mb * 256;
  const int n0 = nb * 128;
  const int tid = threadIdx.x;
  const int lane = tid & 63;
  const int wave = tid >> 6;
  const int wm = (wave >> 1) * 64, wn = (wave & 1) * 64;
  const int l15 = lane & 15, lq = lane >> 4;
  const int rsw = (l15 & 7) << 3;

  __shared__ __half As[2][256][64];   // 64 KB
  __shared__ __half Bs[2][128][64];   // 32 KB

  f32x4 acc[4][4];
#pragma unroll
  for (int i = 0; i < 4; ++i)
#pragma unroll
    for (int j = 0; j < 4; ++j) acc[i][j] = {0.f, 0.f, 0.f, 0.f};

  // staging maps
  const int arow = tid >> 1, acol0 = (tid & 1) * 32, asw = (arow & 7) << 3;
  const int qrow = tid >> 2, qcol0 = (tid & 3) * 16, qsw = (qrow & 7) << 3;
  const __half* aP = Xh + (size_t)(m0 + arow) * H + acol0;
  const int*    qP = Q  + (size_t)(n0 + qrow) * H + qcol0;
  const float*  sP = S + (size_t)(n0 + qrow) * G;
  const float*  zP = Z + (size_t)(n0 + qrow) * G;

  // two named prefetch sets (static indexing, rule #20)
  s16x8 aA[4], aB[4];
  int4  qA[4], qB[4];
  float sA, zA, sB, zB;

#define LOAD_SET(set, kk)                                         \
  {                                                               \
    const int _k = (kk);                                          \
    _Pragma("unroll")                                             \
    for (int i = 0; i < 4; ++i) a##set[i] = ((const s16x8*)(aP + _k))[i]; \
    _Pragma("unroll")                                             \
    for (int i = 0; i < 4; ++i) q##set[i] = ((const int4*)(qP + _k))[i];  \
    s##set = sP[_k >> 7]; z##set = zP[_k >> 7];                   \
  }
#define WRITE_SET(buf, set)                                       \
  {                                                               \
    _Pragma("unroll")                                             \
    for (int i = 0; i < 4; ++i)                                   \
      *(s16x8*)&As[buf][arow][(acol0 + i * 8) ^ asw] = a##set[i]; \
    *(s16x8*)&Bs[buf][qrow][(qcol0 + 0) ^ qsw] = dq_compute(q##set[0], q##set[1], s##set, z##set); \
    *(s16x8*)&Bs[buf][qrow][(qcol0 + 8) ^ qsw] = dq_compute(q##set[2], q##set[3], s##set, z##set); \
  }
#define MFMA_BUF(buf)                                             \
  {                                                               \
    __builtin_amdgcn_s_setprio(1);                                \
    _Pragma("unroll")                                             \
    for (int kk = 0; kk < 2; ++kk) {                              \
      const int cbase = (kk * 32 + lq * 8) ^ rsw;                 \
      f16x8 af[4];                                                \
      _Pragma("unroll")                                           \
      for (int i = 0; i < 4; ++i)                                 \
        af[i] = *(const f16x8*)&As[buf][wm + i * 16 + l15][cbase];\
      _Pragma("unroll")                                           \
      for (int j = 0; j < 4; ++j) {                               \
        f16x8 bf = *(const f16x8*)&Bs[buf][wn + j * 16 + l15][cbase]; \
        _Pragma("unroll")                                         \
        for (int i = 0; i < 4; ++i)                               \
          acc[i][j] = __builtin_amdgcn_mfma_f32_16x16x32_f16(af[i], bf, acc[i][j], 0, 0, 0); \
      }                                                           \
    }                                                             \
    __builtin_amdgcn_s_setprio(0);                                \
  }

  const int nt = H / 64;  // 64, even
  // ---- prologue: tiles 0,1 to regs; tile 0 -> buf 0 ----
  LOAD_SET(A, 0)
  LOAD_SET(B, 64)
  WRITE_SET(0, A)
  __syncthreads();

  for (int t = 0; t < nt; t += 2) {
    if (t + 2 < nt) LOAD_SET(A, (t + 2) * 64)   // issue; consumed ~770cyc later
    MFMA_BUF(0)                                  // tile t
    WRITE_SET(1, B)                              // tile t+1 (regsB ready)
    __syncthreads();
    if (t + 3 < nt) LOAD_SET(B, (t + 3) * 64)
    MFMA_BUF(1)                                  // tile t+1
    if (t + 2 < nt) WRITE_SET(0, A)              // tile t+2
    __syncthreads();
  }
#undef LOAD_SET
#undef WRITE_SET
#undef MFMA_BUF

  // ---- epilogue ----
#pragma unroll
  for (int i = 0; i < 4; ++i)
#pragma unroll
    for (int j = 0; j < 4; ++j)
#pragma unroll
      for (int r = 0; r < 4; ++r) {
        const int row = m0 + wm + i * 16 + lq * 4 + r;
        const int col = n0 + wn + j * 16 + l15;
        const size_t idx = (size_t)row * I + col;
        if (EPI == 0) {
          Pan[idx] = __float2half(acc[i][j][r]);
        } else {
          float g = __half2float(Pan[idx]);
          float u = acc[i][j][r];
          Pan[idx] = __float2half((g / (1.f + __expf(-g))) * u);
        }
      }
}

// ---------------------------------------------------------------------------
// Down GEMM, M-chunked, full-K: out = h @ Wd^T. Same 2-deep pipeline. K=11008.
// ---------------------------------------------------------------------------
__global__ __launch_bounds__(512, 2)
void down_kernel(const __half* __restrict__ Hws,
                 const int* __restrict__ Qd,
                 const float* __restrict__ Sd, const float* __restrict__ Zd,
                 float* __restrict__ Out, int mbs) {
  constexpr int K = 11008, N = 4096, G = 86;
  const int wg = xcd_swz(blockIdx.x, gridDim.x);
  const int mb = wg % mbs;
  const int nb = wg / mbs;
  const int m0 = mb * 256, n0 = nb * 128;
  const int tid = threadIdx.x;
  const int lane = tid & 63;
  const int wave = tid >> 6;
  const int wm = (wave >> 1) * 64, wn = (wave & 1) * 64;
  const int l15 = lane & 15, lq = lane >> 4;
  const int rsw = (l15 & 7) << 3;

  __shared__ __half As[2][256][64];
  __shared__ __half Bs[2][128][64];

  f32x4 acc[4][4];
#pragma unroll
  for (int i = 0; i < 4; ++i)
#pragma unroll
    for (int j = 0; j < 4; ++j) acc[i][j] = {0.f, 0.f, 0.f, 0.f};

  const int arow = tid >> 1, acol0 = (tid & 1) * 32, asw = (arow & 7) << 3;
  const int qrow = tid >> 2, qcol0 = (tid & 3) * 16, qsw = (qrow & 7) << 3;
  const __half* aP = Hws + (size_t)(m0 + arow) * K + acol0;
  const int*    qP = Qd  + (size_t)(n0 + qrow) * K + qcol0;
  const float*  sP = Sd + (size_t)(n0 + qrow) * G;
  const float*  zP = Zd + (size_t)(n0 + qrow) * G;

  s16x8 aA[4], aB[4];
  int4  qA[4], qB[4];
  float sA, zA, sB, zB;

#define LOAD_SET(set, kk)                                         \
  {                                                               \
    const int _k = (kk);                                          \
    _Pragma("unroll")                                             \
    for (int i = 0; i < 4; ++i) a##set[i] = ((const s16x8*)(aP + _k))[i]; \
    _Pragma("unroll")                                             \
    for (int i = 0; i < 4; ++i) q##set[i] = ((const int4*)(qP + _k))[i];  \
    s##set = sP[_k >> 7]; z##set = zP[_k >> 7];                   \
  }
#define WRITE_SET(buf, set)                                       \
  {                                                               \
    _Pragma("unroll")                                             \
    for (int i = 0; i < 4; ++i)                                   \
      *(s16x8*)&As[buf][arow][(acol0 + i * 8) ^ asw] = a##set[i]; \
    *(s16x8*)&Bs[buf][qrow][(qcol0 + 0) ^ qsw] = dq_compute(q##set[0], q##set[1], s##set, z##set); \
    *(s16x8*)&Bs[buf][qrow][(qcol0 + 8) ^ qsw] = dq_compute(q##set[2], q##set[3], s##set, z##set); \
  }
#define MFMA_BUF(buf)                                             \
  {                                                               \
    __builtin_amdgcn_s_setprio(1);                                \
    _Pragma("unroll")                                             \
    for (int kk = 0; kk < 2; ++kk) {                              \
      const int cbase = (kk * 32 + lq * 8) ^ rsw;                 \
      f16x8 af[4];                                                \
      _Pragma("unroll")                                           \
      for (int i = 0; i < 4; ++i)                                 \
        af[i] = *(const f16x8*)&As[buf][wm + i * 16 + l15][cbase];\
      _Pragma("unroll")                                           \
      for (int j = 0; j < 4; ++j) {                               \
        f16x8 bf = *(const f16x8*)&Bs[buf][wn + j * 16 + l15][cbase]; \
        _Pragma("unroll")                                         \
        for (int i = 0; i < 4; ++i)                               \
          acc[i][j] = __builtin_amdgcn_mfma_f32_16x16x32_f16(af[i], bf, acc[i][j], 0, 0, 0); \
      }                                                           \
    }                                                             \
    __builtin_amdgcn_s_setprio(0);                                \
  }

  const int nt = K / 64;  // 172, even
  LOAD_SET(A, 0)
  LOAD_SET(B, 64)
  WRITE_SET(0, A)
  __syncthreads();

  for (int t = 0; t < nt; t += 2) {
    if (t + 2 < nt) LOAD_SET(A, (t + 2) * 64)
    MFMA_BUF(0)
    WRITE_SET(1, B)
    __syncthreads();
    if (t + 3 < nt) LOAD_SET(B, (t + 3) * 64)
    MFMA_BUF(1)
    if (t + 2 < nt) WRITE_SET(0, A)
    __syncthreads();
  }
#undef LOAD_SET
#undef WRITE_SET
#undef MFMA_BUF

#pragma unroll
  for (int i = 0; i < 4; ++i)
#pragma unroll
    for (int j = 0; j < 4; ++j)
#pragma unroll
      for (int r = 0; r < 4; ++r) {
        const int row = m0 + wm + i * 16 + lq * 4 + r;
        const int col = n0 + wn + j * 16 + l15;
        Out[(size_t)row * N + col] = acc[i][j][r];
      }
}

// ---------------------------------------------------------------------------
extern "C" void kernel_launch(void* const* d_in, const int* in_sizes, int n_in,
                              void* d_out, int out_size, void* d_ws, size_t ws_size,
                              hipStream_t stream) {
  const float* x  = (const float*)d_in[0];
  const int* qg   = (const int*)d_in[1];
  const int* qu   = (const int*)d_in[2];
  const int* qd   = (const int*)d_in[3];
  const float* sg = (const float*)d_in[4];
  const float* zg = (const float*)d_in[5];
  const float* su = (const float*)d_in[6];
  const float* zu = (const float*)d_in[7];
  const float* sd = (const float*)d_in[8];
  const float* zd = (const float*)d_in[9];
  float* out = (float*)d_out;

  const int M = 8192, H = 4096, I = 11008;

  // M-chunking: x fp16 chunk + h panel chunk in ws. Mc multiple of 256.
  const size_t per_row = (size_t)(H + I) * 2;
  long mc = (long)(ws_size / per_row);
  mc &= ~255L;
  if (mc > M) mc = M;
  if (mc < 256) mc = 256;
  const int Mc = (int)mc;

  __half* wsx = (__half*)d_ws;
  __half* wsh = (__half*)((char*)d_ws + (size_t)Mc * H * 2);

  for (int mbase = 0; mbase < M; mbase += Mc) {
    const int rows = (M - mbase < Mc) ? (M - mbase) : Mc;
    const int mbs = rows / 256;
    cvt_f32_to_f16_kernel<<<1024, 256, 0, stream>>>(
        x + (size_t)mbase * H, wsx, (long)rows * H);
    qgemm_x_kernel<0><<<mbs * (I / 128), 512, 0, stream>>>(
        wsx, qg, sg, zg, wsh, mbs);
    qgemm_x_kernel<1><<<mbs * (I / 128), 512, 0, stream>>>(
        wsx, qu, su, zu, wsh, mbs);
    down_kernel<<<mbs * (H / 128), 512, 0, stream>>>(
        wsh, qd, sd, zd, out + (size_t)mbase * H, mbs);
  }
}